// Round 7
// baseline (203.698 us; speedup 1.0000x reference)
//
#include <hip/hip_runtime.h>
#include <math.h>

#define H 1024
#define S 32768
#define NPART 16          // d-partials for the W^T @ hidden matvec
#define NB2 512           // K2 blocks: 2/CU, whole grid resident
#define ROWS_PER_BLK 64   // S / NB2
#define TROWS 8           // rows per LDS tile (32 KB)
#define NTILES 8          // ROWS_PER_BLK / TROWS

// ws layout (floats):
//   [0, 16384)        part[p][h]   p<16, h<1024
//   [16384, 16896)    pm[NB2]      per-block softmax max
//   [16896, 17408)    ps[NB2]      per-block softmax sumexp
//   [17408, 50176)    scores[S]
#define WS_PART   0
#define WS_PM     16384
#define WS_PS     16896
#define WS_SCORES 17408

// ---------------------------------------------------------------------------
// K1: part[by][h] = sum_{d in by-chunk of 64} W[d][h] * hidden[d]
// grid (16,16), block 256. One block per CU, coalesced W reads.
// ---------------------------------------------------------------------------
__global__ __launch_bounds__(256) void matvec_partial(const float* __restrict__ W,
                                                      const float* __restrict__ hidden,
                                                      float* __restrict__ ws) {
    float* part = ws + WS_PART;
    const int t  = threadIdx.x;
    const int l  = t & 63;
    const int dg = t >> 6;
    const int h  = blockIdx.x * 64 + l;
    const int d0 = blockIdx.y * 64 + dg * 16;

    float acc = 0.f;
#pragma unroll
    for (int i = 0; i < 16; ++i)
        acc += W[(size_t)(d0 + i) * H + h] * hidden[d0 + i];

    __shared__ float red[4][64];
    red[dg][l] = acc;
    __syncthreads();
    if (t < 64)
        part[blockIdx.y * H + blockIdx.x * 64 + l] =
            red[0][l] + red[1][l] + red[2][l] + red[3][l];
}

// ---------------------------------------------------------------------------
// K2: enc staged into LDS via global_load_lds (async DMA, zero VGPR payload
// -> MLP decoupled from register file; 32 KB/block in flight ~ 64 KB/CU,
// vs the 9.2 KB/CU Little's-law requirement that register-carried loads
// could never meet). Double-buffered 8-row tiles; loop = barrier (drains
// tile t) -> issue stage(t+1) -> compute(t); the prefetch streams under
// compute's ds_reads (lgkmcnt path, independent of vmcnt).
// ---------------------------------------------------------------------------
__device__ __forceinline__ float4 add4(float4 a, float4 b) {
    return make_float4(a.x + b.x, a.y + b.y, a.z + b.z, a.w + b.w);
}

__device__ __forceinline__ void gload_lds16(const float* g, float* l) {
    __builtin_amdgcn_global_load_lds(
        (const __attribute__((address_space(1))) void*)g,
        (__attribute__((address_space(3))) void*)l, 16, 0, 0);
}

__global__ __launch_bounds__(256, 2) void scores_partial(const float* __restrict__ enc,
                                                         float* __restrict__ ws) {
    float* scores = ws + WS_SCORES;
    float* pm     = ws + WS_PM;
    float* ps     = ws + WS_PS;
    const float* part = ws + WS_PART;

    const int tid  = threadIdx.x;
    const int lane = tid & 63;
    const int wv   = tid >> 6;
    const int blk  = blockIdx.x;
    const size_t row_base = (size_t)blk * ROWS_PER_BLK;

    __shared__ float tile[2][TROWS * H];   // 2 x 32 KB
    __shared__ float vsh[H];               // 4 KB
    __shared__ float sm[4], ss[4];

    const float* enc_blk = enc + row_base * H;

    // stage(tile 0) FIRST: DMA in flight while the v-prologue runs
    // wave wv stages chunks wv*8..wv*8+7; chunk c = (row c>>2, quarter c&3)
#pragma unroll
    for (int i = 0; i < 8; ++i) {
        const int c = wv * 8 + i;
        gload_lds16(enc_blk + (size_t)(c >> 2) * H + (c & 3) * 256 + lane * 4,
                    &tile[0][c * 256]);
    }

    // --- v-rebuild prologue: 16 independent L2 loads, tree sum, LDS ---
    {
        const float4* p4 = (const float4*)part;
        float4 t[NPART];
#pragma unroll
        for (int p = 0; p < NPART; ++p) t[p] = p4[p * (H / 4) + tid];
#pragma unroll
        for (int p = 0; p < 8; ++p) t[p] = add4(t[p], t[p + 8]);
#pragma unroll
        for (int p = 0; p < 4; ++p) t[p] = add4(t[p], t[p + 4]);
        ((float4*)vsh)[tid] = add4(add4(t[0], t[2]), add4(t[1], t[3]));
    }
    __syncthreads();                       // vsh visible + tile0 DMA drained

    float4 vf[4];
#pragma unroll
    for (int k = 0; k < 4; ++k) vf[k] = ((const float4*)vsh)[lane + 64 * k];

    float sa[2 * NTILES];                  // this wave's 16 row scores

#pragma unroll
    for (int t = 0; t < NTILES; ++t) {
        // issue next tile's DMA before computing this one
        if (t + 1 < NTILES) {
            float* buf = tile[(t + 1) & 1];
#pragma unroll
            for (int i = 0; i < 8; ++i) {
                const int c = wv * 8 + i;
                gload_lds16(enc_blk + (size_t)((t + 1) * TROWS + (c >> 2)) * H +
                                (c & 3) * 256 + lane * 4,
                            &buf[c * 256]);
            }
        }

        // compute rows wv*2, wv*2+1 of tile t from LDS
        const float* tb = tile[t & 1];
#pragma unroll
        for (int j = 0; j < 2; ++j) {
            const float4* r4 = (const float4*)(tb + (wv * 2 + j) * H);
            const float4 e0 = r4[lane],       e1 = r4[lane + 64],
                         e2 = r4[lane + 128], e3 = r4[lane + 192];
            float s0 = e0.x * vf[0].x + e0.y * vf[0].y + e0.z * vf[0].z + e0.w * vf[0].w;
            float s1 = e1.x * vf[1].x + e1.y * vf[1].y + e1.z * vf[1].z + e1.w * vf[1].w;
            float s2 = e2.x * vf[2].x + e2.y * vf[2].y + e2.z * vf[2].z + e2.w * vf[2].w;
            float s3 = e3.x * vf[3].x + e3.y * vf[3].y + e3.z * vf[3].z + e3.w * vf[3].w;
            float a = (s0 + s1) + (s2 + s3);
#pragma unroll
            for (int off = 32; off > 0; off >>= 1)
                a += __shfl_xor(a, off, 64);
            sa[t * 2 + j] = a;
        }
        if (lane == 0)
            *(float2*)(scores + row_base + t * TROWS + wv * 2) =
                make_float2(sa[t * 2], sa[t * 2 + 1]);

        __syncthreads();                   // all reads of tile[t&1] done; next
                                           // iter's barrier-drain covers t+1
    }

    // deferred wave softmax partial over 16 rows
    float mw = sa[0];
#pragma unroll
    for (int i = 1; i < 2 * NTILES; ++i) mw = fmaxf(mw, sa[i]);
    float sw = 0.f;
#pragma unroll
    for (int i = 0; i < 2 * NTILES; ++i) sw += __expf(sa[i] - mw);

    if (lane == 0) { sm[wv] = mw; ss[wv] = sw; }
    __syncthreads();
    if (tid == 0) {
        float m = sm[0], s = ss[0];
#pragma unroll
        for (int i = 1; i < 4; ++i) {
            const float nm = fmaxf(m, sm[i]);
            s = s * __expf(m - nm) + ss[i] * __expf(sm[i] - nm);
            m = nm;
        }
        pm[blk] = m; ps[blk] = s;
    }
}

// ---------------------------------------------------------------------------
// K3: every block redundantly combines the 512 (m,s) pairs, then
// normalizes its 256 scores. grid 128 blocks x 256 threads.
// ---------------------------------------------------------------------------
__global__ __launch_bounds__(256) void finalize(const float* __restrict__ ws,
                                                float* __restrict__ out) {
    const float* scores = ws + WS_SCORES;
    const float* pm     = ws + WS_PM;
    const float* ps     = ws + WS_PS;

    const int tid  = threadIdx.x;
    const int lane = tid & 63;
    const int wv   = tid >> 6;

    float m = -INFINITY, s = 0.f;
#pragma unroll
    for (int i = 0; i < NB2 / 256; ++i) {
        const int idx = tid + i * 256;
        const float om = pm[idx], os = ps[idx];
        const float nm = fmaxf(m, om);
        s = s * __expf(m - nm) + os * __expf(om - nm);
        m = nm;
    }
#pragma unroll
    for (int off = 32; off > 0; off >>= 1) {
        const float om = __shfl_xor(m, off, 64);
        const float os = __shfl_xor(s, off, 64);
        const float nm = fmaxf(m, om);
        s = s * __expf(m - nm) + os * __expf(om - nm);
        m = nm;
    }
    __shared__ float sm[4], ss[4];
    if (lane == 0) { sm[wv] = m; ss[wv] = s; }
    __syncthreads();
    float M = sm[0], Ssum = ss[0];
#pragma unroll
    for (int i = 1; i < 4; ++i) {
        const float nm = fmaxf(M, sm[i]);
        Ssum = Ssum * __expf(M - nm) + ss[i] * __expf(sm[i] - nm);
        M = nm;
    }
    const float rs = 1.0f / Ssum;

    const int i = blockIdx.x * 256 + tid;
    out[i] = __expf(scores[i] - M) * rs;
}

extern "C" void kernel_launch(void* const* d_in, const int* in_sizes, int n_in,
                              void* d_out, int out_size, void* d_ws, size_t ws_size,
                              hipStream_t stream) {
    const float* hidden = (const float*)d_in[0];   // [H]
    const float* enc    = (const float*)d_in[1];   // [S, H]
    const float* W      = (const float*)d_in[2];   // [H, H]
    // d_in[3] = b — unused: b·hidden is a uniform softmax shift (cancels exactly).
    float* out = (float*)d_out;                    // [S] fp32
    float* ws  = (float*)d_ws;

    matvec_partial<<<dim3(16, 16), 256, 0, stream>>>(W, hidden, ws);
    scores_partial<<<NB2, 256, 0, stream>>>(enc, ws);
    finalize<<<S / 256, 256, 0, stream>>>(ws, out);
}